// Round 1
// baseline (679.184 us; speedup 1.0000x reference)
//
#include <hip/hip_runtime.h>

// Problem: B=64, N=257, D=1024, H=16, HD=64
#define B_   64
#define N_   257
#define D_   1024
#define H_   16
#define HD_  64
#define M_   (B_*N_)      // 16448 rows (b*257+n)
#define MPAD 16512        // 129 * 128 (M padded to 128-tiles)
#define E3_  3072
#define CK_  96           // attention key-chunk (3 chunks cover 288 >= 257)

typedef __bf16 bf16x8 __attribute__((ext_vector_type(8)));
typedef __bf16 bf16x4 __attribute__((ext_vector_type(4)));
typedef float  f32x4  __attribute__((ext_vector_type(4)));

// ---------------- f32 -> bf16 convert (vectorized) ----------------
__global__ __launch_bounds__(256) void cvt_f32_bf16(const float* __restrict__ src,
                                                    __bf16* __restrict__ dst, int n4) {
    int i = blockIdx.x * 256 + threadIdx.x;
    if (i >= n4) return;
    float4 v = reinterpret_cast<const float4*>(src)[i];
    bf16x4 o;
    o[0] = (__bf16)v.x; o[1] = (__bf16)v.y; o[2] = (__bf16)v.z; o[3] = (__bf16)v.w;
    *reinterpret_cast<bf16x4*>(dst + (size_t)i * 4) = o;
}

// ---------------- QKV projection GEMM (bt): C[m][e] = sum_k x[m][k]*W[e][k] + b[e] ----------------
// Scatters to q[b][h][n][hd] (scaled 1/8), k[b][h][n][hd], v[b][h][hd][n] (transposed).
__global__ __launch_bounds__(256) void qkv_gemm(const __bf16* __restrict__ A,
                                                const __bf16* __restrict__ W,
                                                const float* __restrict__ bias,
                                                __bf16* __restrict__ qw,
                                                __bf16* __restrict__ kw,
                                                __bf16* __restrict__ vw) {
    __shared__ __align__(16) __bf16 As[128 * 32];
    __shared__ __align__(16) __bf16 Ws[128 * 32];
    const int tid  = threadIdx.x;
    const int row0 = blockIdx.x * 128, col0 = blockIdx.y * 128;
    const int lane = tid & 63, wv = tid >> 6;
    const int wm = (wv >> 1) * 64, wn = (wv & 1) * 64;
    const int fr = lane & 15, fq = lane >> 4;
    f32x4 acc[4][4] = {};
    for (int k0 = 0; k0 < 1024; k0 += 32) {
#pragma unroll
        for (int i = 0; i < 2; ++i) {
            int c = tid + i * 256;
            int r = c >> 2, off = (c & 3) * 8;
            *reinterpret_cast<uint4*>(&As[r * 32 + off]) =
                *reinterpret_cast<const uint4*>(A + (size_t)(row0 + r) * 1024 + k0 + off);
            *reinterpret_cast<uint4*>(&Ws[r * 32 + off]) =
                *reinterpret_cast<const uint4*>(W + (size_t)(col0 + r) * 1024 + k0 + off);
        }
        __syncthreads();
        bf16x8 af[4], bfr[4];
#pragma unroll
        for (int i = 0; i < 4; ++i)
            af[i] = *reinterpret_cast<const bf16x8*>(&As[(wm + i * 16 + fr) * 32 + fq * 8]);
#pragma unroll
        for (int j = 0; j < 4; ++j)
            bfr[j] = *reinterpret_cast<const bf16x8*>(&Ws[(wn + j * 16 + fr) * 32 + fq * 8]);
#pragma unroll
        for (int i = 0; i < 4; ++i)
#pragma unroll
            for (int j = 0; j < 4; ++j)
                acc[i][j] = __builtin_amdgcn_mfma_f32_16x16x32_bf16(af[i], bfr[j], acc[i][j], 0, 0, 0);
        __syncthreads();
    }
    // epilogue: C row = row0+wm+i*16+fq*4+r, col = col0+wn+j*16+fr
#pragma unroll
    for (int i = 0; i < 4; ++i) {
#pragma unroll
        for (int r = 0; r < 4; ++r) {
            const int m = row0 + wm + i * 16 + fq * 4 + r;
            if (m < M_) {
                const int bb = m / 257, nn = m % 257;
#pragma unroll
                for (int j = 0; j < 4; ++j) {
                    const int e = col0 + wn + j * 16 + fr;
                    const float val = acc[i][j][r] + bias[e];
                    const int which = e >> 10;
                    const int h = (e >> 6) & 15, hd = e & 63;
                    if (which == 0)
                        qw[((size_t)(bb * 16 + h) * 257 + nn) * 64 + hd] = (__bf16)(val * 0.125f);
                    else if (which == 1)
                        kw[((size_t)(bb * 16 + h) * 257 + nn) * 64 + hd] = (__bf16)val;
                    else
                        vw[((size_t)(bb * 16 + h) * 64 + hd) * 257 + nn] = (__bf16)val;
                }
            }
        }
    }
}

// ---------------- fused masked attention (flash-style, 3 key chunks of 96) ----------------
__global__ __launch_bounds__(256) void attn_kernel(const __bf16* __restrict__ qw,
                                                   const __bf16* __restrict__ kw,
                                                   const __bf16* __restrict__ vw,
                                                   const int* __restrict__ mask,
                                                   __bf16* __restrict__ attn) {
    const int bh = blockIdx.x;
    const int bb = bh >> 4, hh = bh & 15;
    const int q0 = blockIdx.y * 64;
    const int tid = threadIdx.x, lane = tid & 63, wv = tid >> 6;
    const int fr = lane & 15, fq = lane >> 4;
    const float NEG_INF = -__builtin_inff();

    __shared__ __align__(16) __bf16 Qs[64 * 64];
    __shared__ __align__(16) __bf16 Ks[CK_ * 64];
    __shared__ __align__(16) __bf16 Vt[64 * CK_];
    __shared__ __align__(16) __bf16 Pl[4][16 * CK_];
    __shared__ float maskb[CK_];

    // stage Q tile [64 rows][64], zero rows past N
    const __bf16* qg = qw + ((size_t)bh * 257 + q0) * 64;
#pragma unroll
    for (int i = 0; i < 2; ++i) {
        int c = tid + i * 256;
        int r = c >> 3, off = (c & 7) * 8;
        uint4 v = {0, 0, 0, 0};
        if (q0 + r < 257) v = *reinterpret_cast<const uint4*>(qg + (size_t)r * 64 + off);
        *reinterpret_cast<uint4*>(&Qs[r * 64 + off]) = v;
    }

    float m_run[4] = {NEG_INF, NEG_INF, NEG_INF, NEG_INF};
    float l_run[4] = {};
    f32x4 Oa[4] = {};

    const __bf16* kg = kw + (size_t)bh * 257 * 64;
    const __bf16* vg = vw + (size_t)bh * 64 * 257;
    const int* mg = mask + bb * 257;

    for (int c3 = 0; c3 < 3; ++c3) {
        const int k0 = c3 * CK_;
        __syncthreads();  // prior chunk readers done before restage (also publishes Qs on c3==0)
        // stage K chunk [96 keys][64], zero rows past N
#pragma unroll
        for (int i = 0; i < 3; ++i) {
            int c = tid + i * 256;
            int r = c >> 3, off = (c & 7) * 8;
            uint4 v = {0, 0, 0, 0};
            if (k0 + r < 257) v = *reinterpret_cast<const uint4*>(kg + (size_t)(k0 + r) * 64 + off);
            *reinterpret_cast<uint4*>(&Ks[r * 64 + off]) = v;
        }
        // stage V^T chunk [64 hd][96 keys], zero cols past N
        for (int idx = tid; idx < 64 * CK_; idx += 256) {
            int r = idx / CK_, jj = idx - r * CK_;
            __bf16 v = (__bf16)0.0f;
            if (k0 + jj < 257) v = vg[(size_t)r * 257 + k0 + jj];
            Vt[r * CK_ + jj] = v;
        }
        if (tid < CK_) {
            int j = k0 + tid;
            maskb[tid] = (j < 257 && mg[j] == 0) ? 0.0f : NEG_INF;
        }
        __syncthreads();

        // S = Q K^T (+ mask bias); q pre-scaled by 1/8
        bf16x8 aq[2];
#pragma unroll
        for (int ks = 0; ks < 2; ++ks)
            aq[ks] = *reinterpret_cast<const bf16x8*>(&Qs[(wv * 16 + fr) * 64 + ks * 32 + fq * 8]);
        f32x4 s[6];
#pragma unroll
        for (int nt = 0; nt < 6; ++nt) {
            f32x4 sa = {};
#pragma unroll
            for (int ks = 0; ks < 2; ++ks) {
                bf16x8 bk = *reinterpret_cast<const bf16x8*>(&Ks[(nt * 16 + fr) * 64 + ks * 32 + fq * 8]);
                sa = __builtin_amdgcn_mfma_f32_16x16x32_bf16(aq[ks], bk, sa, 0, 0, 0);
            }
            const float mb = maskb[nt * 16 + fr];
#pragma unroll
            for (int r = 0; r < 4; ++r) sa[r] += mb;
            s[nt] = sa;
        }
        // online softmax: row r lives in the 16 lanes of this quad (row = fq*4+r)
        float alpha[4];
#pragma unroll
        for (int r = 0; r < 4; ++r) {
            float v = s[0][r];
#pragma unroll
            for (int nt = 1; nt < 6; ++nt) v = fmaxf(v, s[nt][r]);
            v = fmaxf(v, __shfl_xor(v, 1));
            v = fmaxf(v, __shfl_xor(v, 2));
            v = fmaxf(v, __shfl_xor(v, 4));
            v = fmaxf(v, __shfl_xor(v, 8));
            const float mnew = fmaxf(m_run[r], v);
            alpha[r] = __expf(m_run[r] - mnew);
            m_run[r] = mnew;
        }
        float sm[4] = {};
#pragma unroll
        for (int nt = 0; nt < 6; ++nt)
#pragma unroll
            for (int r = 0; r < 4; ++r) {
                const float p = __expf(s[nt][r] - m_run[r]);
                s[nt][r] = p;
                sm[r] += p;
            }
#pragma unroll
        for (int r = 0; r < 4; ++r) {
            float v = sm[r];
            v += __shfl_xor(v, 1);
            v += __shfl_xor(v, 2);
            v += __shfl_xor(v, 4);
            v += __shfl_xor(v, 8);
            l_run[r] = l_run[r] * alpha[r] + v;
        }
#pragma unroll
        for (int ot = 0; ot < 4; ++ot)
#pragma unroll
            for (int r = 0; r < 4; ++r) Oa[ot][r] *= alpha[r];
        // P: C-layout -> A-layout via LDS round-trip (per-wave buffer)
#pragma unroll
        for (int nt = 0; nt < 6; ++nt)
#pragma unroll
            for (int r = 0; r < 4; ++r)
                Pl[wv][(fq * 4 + r) * CK_ + nt * 16 + fr] = (__bf16)s[nt][r];
        __syncthreads();
        // O += P V  (Vt is [hd][key] so this is gemm_bt)
        bf16x8 ap[3];
#pragma unroll
        for (int kk = 0; kk < 3; ++kk)
            ap[kk] = *reinterpret_cast<const bf16x8*>(&Pl[wv][fr * CK_ + kk * 32 + fq * 8]);
#pragma unroll
        for (int ot = 0; ot < 4; ++ot)
#pragma unroll
            for (int kk = 0; kk < 3; ++kk) {
                bf16x8 bv = *reinterpret_cast<const bf16x8*>(&Vt[(ot * 16 + fr) * CK_ + kk * 32 + fq * 8]);
                Oa[ot] = __builtin_amdgcn_mfma_f32_16x16x32_bf16(ap[kk], bv, Oa[ot], 0, 0, 0);
            }
    }
    // epilogue: attn[b][n][h*64+hd] bf16
#pragma unroll
    for (int r = 0; r < 4; ++r) {
        const int n = q0 + wv * 16 + fq * 4 + r;
        if (n < 257) {
            const float inv = 1.0f / l_run[r];
#pragma unroll
            for (int ot = 0; ot < 4; ++ot) {
                const int hd = ot * 16 + fr;
                attn[((size_t)(bb * 257 + n)) * 1024 + hh * 64 + hd] = (__bf16)(Oa[ot][r] * inv);
            }
        }
    }
}

// ---------------- output projection GEMM (bt) + bias -> f32 d_out ----------------
__global__ __launch_bounds__(256) void out_gemm(const __bf16* __restrict__ A,
                                                const __bf16* __restrict__ W,
                                                const float* __restrict__ bias,
                                                float* __restrict__ out) {
    __shared__ __align__(16) __bf16 As[128 * 32];
    __shared__ __align__(16) __bf16 Ws[128 * 32];
    const int tid  = threadIdx.x;
    const int row0 = blockIdx.x * 128, col0 = blockIdx.y * 128;
    const int lane = tid & 63, wv = tid >> 6;
    const int wm = (wv >> 1) * 64, wn = (wv & 1) * 64;
    const int fr = lane & 15, fq = lane >> 4;
    f32x4 acc[4][4] = {};
    for (int k0 = 0; k0 < 1024; k0 += 32) {
#pragma unroll
        for (int i = 0; i < 2; ++i) {
            int c = tid + i * 256;
            int r = c >> 2, off = (c & 3) * 8;
            *reinterpret_cast<uint4*>(&As[r * 32 + off]) =
                *reinterpret_cast<const uint4*>(A + (size_t)(row0 + r) * 1024 + k0 + off);
            *reinterpret_cast<uint4*>(&Ws[r * 32 + off]) =
                *reinterpret_cast<const uint4*>(W + (size_t)(col0 + r) * 1024 + k0 + off);
        }
        __syncthreads();
        bf16x8 af[4], bfr[4];
#pragma unroll
        for (int i = 0; i < 4; ++i)
            af[i] = *reinterpret_cast<const bf16x8*>(&As[(wm + i * 16 + fr) * 32 + fq * 8]);
#pragma unroll
        for (int j = 0; j < 4; ++j)
            bfr[j] = *reinterpret_cast<const bf16x8*>(&Ws[(wn + j * 16 + fr) * 32 + fq * 8]);
#pragma unroll
        for (int i = 0; i < 4; ++i)
#pragma unroll
            for (int j = 0; j < 4; ++j)
                acc[i][j] = __builtin_amdgcn_mfma_f32_16x16x32_bf16(af[i], bfr[j], acc[i][j], 0, 0, 0);
        __syncthreads();
    }
#pragma unroll
    for (int i = 0; i < 4; ++i)
#pragma unroll
        for (int r = 0; r < 4; ++r) {
            const int m = row0 + wm + i * 16 + fq * 4 + r;
            if (m < M_) {
#pragma unroll
                for (int j = 0; j < 4; ++j) {
                    const int e = col0 + wn + j * 16 + fr;
                    out[(size_t)m * 1024 + e] = acc[i][j][r] + bias[e];
                }
            }
        }
}

// ---------------- launch ----------------
// ws layout (bytes):
//   x_bf   @ 0          : MPAD*1024*2      = 33,816,576
//   w1_bf  @ 33816576   : 3072*1024*2      =  6,291,456
//   w2_bf  @ 40108032   : 1024*1024*2      =  2,097,152
//   q_ws   @ 42205184   : 64*16*257*64*2   = 33,685,504   [b][h][n][hd], pre-scaled 1/8
//   k_ws   @ 75890688   : 33,685,504                        [b][h][n][hd]
//   v_ws   @ 109576192  : 33,685,504                        [b][h][hd][n] (transposed)
//   a_bf   @ 143261696  : MPAD*1024*2      = 33,816,576   attention output, bf16
// total 177,078,272 B
extern "C" void kernel_launch(void* const* d_in, const int* in_sizes, int n_in,
                              void* d_out, int out_size, void* d_ws, size_t ws_size,
                              hipStream_t stream) {
    const float* x  = (const float*)d_in[0];
    const int* mask = (const int*)d_in[1];
    const float* w1 = (const float*)d_in[2];
    const float* b1 = (const float*)d_in[3];
    const float* w2 = (const float*)d_in[4];
    const float* b2 = (const float*)d_in[5];
    float* out = (float*)d_out;
    char* ws = (char*)d_ws;
    __bf16* x_bf  = (__bf16*)(ws);
    __bf16* w1_bf = (__bf16*)(ws + 33816576);
    __bf16* w2_bf = (__bf16*)(ws + 40108032);
    __bf16* q_ws  = (__bf16*)(ws + 42205184);
    __bf16* k_ws  = (__bf16*)(ws + 75890688);
    __bf16* v_ws  = (__bf16*)(ws + 109576192);
    __bf16* a_bf  = (__bf16*)(ws + 143261696);

    cvt_f32_bf16<<<16448, 256, 0, stream>>>(x, x_bf, 4210688);
    cvt_f32_bf16<<<3072, 256, 0, stream>>>(w1, w1_bf, 786432);
    cvt_f32_bf16<<<1024, 256, 0, stream>>>(w2, w2_bf, 262144);
    qkv_gemm<<<dim3(129, 24), 256, 0, stream>>>(x_bf, w1_bf, b1, q_ws, k_ws, v_ws);
    attn_kernel<<<dim3(1024, 5), 256, 0, stream>>>(q_ws, k_ws, v_ws, mask, a_bf);
    out_gemm<<<dim3(129, 8), 256, 0, stream>>>(a_bf, w2_bf, b2, out);
}

// Round 2
// 469.107 us; speedup vs baseline: 1.4478x; 1.4478x over previous
//
#include <hip/hip_runtime.h>

// Problem: B=64, N=257, D=1024, H=16, HD=64
#define B_   64
#define N_   257
#define D_   1024
#define H_   16
#define HD_  64
#define M_   (B_*N_)      // 16448 rows (b*257+n)
#define MPAD 16512        // 129 * 128
#define CK_  96           // attention key-chunk (3 chunks cover 288 >= 257)
#define PLS_ 104          // Pl row stride (multiple of 8, 8*odd -> fewer bank conflicts)

typedef __bf16 bf16x8 __attribute__((ext_vector_type(8)));
typedef __bf16 bf16x4 __attribute__((ext_vector_type(4)));
typedef float  f32x4  __attribute__((ext_vector_type(4)));

// async global->LDS, 16B per lane; LDS dest = wave-uniform base + lane*16
__device__ __forceinline__ void gload_lds16(const void* g, void* l) {
    __builtin_amdgcn_global_load_lds(
        (const __attribute__((address_space(1))) void*)g,
        (__attribute__((address_space(3))) void*)l, 16, 0, 0);
}

// V^T LDS column-group swizzle: 12 groups of 8 keys, XOR by hd bits (8+4 split)
__device__ __forceinline__ int vswz(int cg, int hd) {
    int s = (hd >> 3) & 7;
    return cg < 8 ? (cg ^ s) : (8 + ((cg & 3) ^ (s & 3)));
}

// ---------------- f32 -> bf16 convert ----------------
__global__ __launch_bounds__(256) void cvt_f32_bf16(const float* __restrict__ src,
                                                    __bf16* __restrict__ dst, int n4) {
    int i = blockIdx.x * 256 + threadIdx.x;
    if (i >= n4) return;
    float4 v = reinterpret_cast<const float4*>(src)[i];
    bf16x4 o;
    o[0] = (__bf16)v.x; o[1] = (__bf16)v.y; o[2] = (__bf16)v.z; o[3] = (__bf16)v.w;
    *reinterpret_cast<bf16x4*>(dst + (size_t)i * 4) = o;
}

// ---------------- QKV projection GEMM (bt), m97-style staging ----------------
// All of Q (scaled 1/8), K, V written [b][h][n][hd]; block's 128 e-cols lie in one of q/k/v.
__global__ __launch_bounds__(256) void qkv_gemm(const __bf16* __restrict__ A,
                                                const __bf16* __restrict__ W,
                                                const float* __restrict__ bias,
                                                __bf16* __restrict__ qw,
                                                __bf16* __restrict__ kw,
                                                __bf16* __restrict__ vw) {
    __shared__ __align__(16) __bf16 As[128 * 32];
    __shared__ __align__(16) __bf16 Ws[128 * 32];
    const int tid  = threadIdx.x;
    const int row0 = blockIdx.x * 128, col0 = blockIdx.y * 128;
    const int lane = tid & 63, wv = tid >> 6;
    const int wm = (wv >> 1) * 64, wn = (wv & 1) * 64;
    const int fr = lane & 15, fq = lane >> 4;
    const int c1 = tid + 256;
    const size_t ga0 = (size_t)(row0 + (tid >> 2)) * 1024 + (tid & 3) * 8;
    const size_t ga1 = (size_t)(row0 + (c1 >> 2)) * 1024 + (c1 & 3) * 8;
    const size_t gw0 = (size_t)(col0 + (tid >> 2)) * 1024 + (tid & 3) * 8;
    const size_t gw1 = (size_t)(col0 + (c1 >> 2)) * 1024 + (c1 & 3) * 8;
    char* lbase0 = (char*)As + wv * 1024;
    char* lbase1 = (char*)As + wv * 1024 + 4096;
    char* lbw0 = (char*)Ws + wv * 1024;
    char* lbw1 = (char*)Ws + wv * 1024 + 4096;
    f32x4 acc[4][4] = {};
    for (int k0 = 0; k0 < 1024; k0 += 32) {
        gload_lds16(A + ga0 + k0, lbase0);
        gload_lds16(A + ga1 + k0, lbase1);
        gload_lds16(W + gw0 + k0, lbw0);
        gload_lds16(W + gw1 + k0, lbw1);
        __syncthreads();
        bf16x8 af[4], bfr[4];
#pragma unroll
        for (int i = 0; i < 4; ++i)
            af[i] = *reinterpret_cast<const bf16x8*>(&As[(wm + i * 16 + fr) * 32 + fq * 8]);
#pragma unroll
        for (int j = 0; j < 4; ++j)
            bfr[j] = *reinterpret_cast<const bf16x8*>(&Ws[(wn + j * 16 + fr) * 32 + fq * 8]);
#pragma unroll
        for (int i = 0; i < 4; ++i)
#pragma unroll
            for (int j = 0; j < 4; ++j)
                acc[i][j] = __builtin_amdgcn_mfma_f32_16x16x32_bf16(af[i], bfr[j], acc[i][j], 0, 0, 0);
        __syncthreads();
    }
    // which third: uniform per block (128 | 1024)
    const int which = col0 >> 10;
    __bf16* dst = which == 0 ? qw : (which == 1 ? kw : vw);
    const float scale = which == 0 ? 0.125f : 1.0f;
    float bj[4];
#pragma unroll
    for (int j = 0; j < 4; ++j) bj[j] = bias[col0 + wn + j * 16 + fr];
    const int h = ((col0 + wn + fr) >> 6) & 15;   // same h for all 4 j (hd = j*16+fr spans 0..63)
    const int hdb = fr;
#pragma unroll
    for (int i = 0; i < 4; ++i) {
#pragma unroll
        for (int r = 0; r < 4; ++r) {
            const int m = row0 + wm + i * 16 + fq * 4 + r;
            if (m < M_) {
                const int bb = m / 257, nn = m % 257;
                __bf16* p = dst + ((size_t)(bb * 16 + h) * 257 + nn) * 64 + hdb;
#pragma unroll
                for (int j = 0; j < 4; ++j)
                    p[j * 16] = (__bf16)((acc[i][j][r] + bj[j]) * scale);
            }
        }
    }
}

// ---------------- fused masked attention (flash-style, 3 key chunks of 96) ----------------
__global__ __launch_bounds__(256) void attn_kernel(const __bf16* __restrict__ qw,
                                                   const __bf16* __restrict__ kw,
                                                   const __bf16* __restrict__ vw,
                                                   const int* __restrict__ mask,
                                                   __bf16* __restrict__ attn) {
    const int bh = blockIdx.x;
    const int bb = bh >> 4, hh = bh & 15;
    const int q0 = blockIdx.y * 64;
    const int tid = threadIdx.x, lane = tid & 63, wv = tid >> 6;
    const int fr = lane & 15, fq = lane >> 4;
    const float NEG_INF = -__builtin_inff();

    __shared__ __align__(16) __bf16 Qs[64 * 64];        // [q][hd]
    __shared__ __align__(16) __bf16 Ks[CK_ * 64];       // [key][hd]
    __shared__ __align__(16) __bf16 Vt[64 * CK_];       // [hd][key], column-swizzled
    __shared__ __align__(16) __bf16 Pl[4][16 * PLS_];   // per-wave P, stride PLS_
    __shared__ float maskb[CK_];

    const __bf16* qg = qw + ((size_t)bh * 257 + q0) * 64;
    const __bf16* kg = kw + (size_t)bh * 257 * 64;
    const __bf16* vg = vw + (size_t)bh * 257 * 64;
    const int* mg = mask + bb * 257;

    // stage Q tile [64][64] async; rows past N keep stale LDS (never stored)
    {
        if (q0 + (tid >> 3) < 257)
            gload_lds16(qg + (size_t)(tid >> 3) * 64 + (tid & 7) * 8, (char*)Qs + wv * 1024);
        const int c = tid + 256;
        if (q0 + (c >> 3) < 257)
            gload_lds16(qg + (size_t)(c >> 3) * 64 + (c & 7) * 8, (char*)Qs + wv * 1024 + 4096);
    }

    float m_run[4] = {NEG_INF, NEG_INF, NEG_INF, NEG_INF};
    float l_run[4] = {};
    f32x4 Oa[4] = {};

    for (int c3 = 0; c3 < 3; ++c3) {
        const int k0 = c3 * CK_;
        __syncthreads();  // prior-chunk readers done before restage (also publishes Qs on c3==0)
        // stage K chunk [96][64] async; invalid rows keep stale (masked to -inf anyway)
#pragma unroll
        for (int i = 0; i < 3; ++i) {
            const int c = tid + i * 256;
            if (k0 + (c >> 3) < 257)
                gload_lds16(kg + (size_t)(k0 + (c >> 3)) * 64 + (c & 7) * 8,
                            (char*)Ks + wv * 1024 + i * 4096);
        }
        // stage V^T: coalesced uint4 reads of V[key][hd], swizzled scalar LDS writes
#pragma unroll
        for (int it = 0; it < 3; ++it) {
            const int t = tid + it * 256;
            const int key = t >> 3, grp = t & 7;
            if (k0 + key < 257) {
                bf16x8 v8 = *reinterpret_cast<const bf16x8*>(vg + (size_t)(k0 + key) * 64 + grp * 8);
#pragma unroll
                for (int u = 0; u < 8; ++u) {
                    const int hd = grp * 8 + u;
                    Vt[hd * CK_ + vswz(key >> 3, hd) * 8 + (key & 7)] = v8[u];
                }
            }
        }
        if (tid < CK_) {
            const int j = k0 + tid;
            maskb[tid] = (j < 257 && mg[j] == 0) ? 0.0f : NEG_INF;
        }
        __syncthreads();

        // S = Q K^T (+ mask bias); q pre-scaled by 1/8
        bf16x8 aq[2];
#pragma unroll
        for (int ks = 0; ks < 2; ++ks)
            aq[ks] = *reinterpret_cast<const bf16x8*>(&Qs[(wv * 16 + fr) * 64 + ks * 32 + fq * 8]);
        f32x4 s[6];
#pragma unroll
        for (int nt = 0; nt < 6; ++nt) {
            f32x4 sa = {};
#pragma unroll
            for (int ks = 0; ks < 2; ++ks) {
                bf16x8 bk = *reinterpret_cast<const bf16x8*>(&Ks[(nt * 16 + fr) * 64 + ks * 32 + fq * 8]);
                sa = __builtin_amdgcn_mfma_f32_16x16x32_bf16(aq[ks], bk, sa, 0, 0, 0);
            }
            const float mb = maskb[nt * 16 + fr];
#pragma unroll
            for (int r = 0; r < 4; ++r) sa[r] += mb;
            s[nt] = sa;
        }
        // online softmax (row = fq*4+r, spread over 16 lanes)
        float alpha[4];
#pragma unroll
        for (int r = 0; r < 4; ++r) {
            float v = s[0][r];
#pragma unroll
            for (int nt = 1; nt < 6; ++nt) v = fmaxf(v, s[nt][r]);
            v = fmaxf(v, __shfl_xor(v, 1));
            v = fmaxf(v, __shfl_xor(v, 2));
            v = fmaxf(v, __shfl_xor(v, 4));
            v = fmaxf(v, __shfl_xor(v, 8));
            const float mnew = fmaxf(m_run[r], v);
            alpha[r] = __expf(m_run[r] - mnew);
            m_run[r] = mnew;
        }
        float sm[4] = {};
#pragma unroll
        for (int nt = 0; nt < 6; ++nt)
#pragma unroll
            for (int r = 0; r < 4; ++r) {
                const float p = __expf(s[nt][r] - m_run[r]);
                s[nt][r] = p;
                sm[r] += p;
            }
#pragma unroll
        for (int r = 0; r < 4; ++r) {
            float v = sm[r];
            v += __shfl_xor(v, 1);
            v += __shfl_xor(v, 2);
            v += __shfl_xor(v, 4);
            v += __shfl_xor(v, 8);
            l_run[r] = l_run[r] * alpha[r] + v;
        }
#pragma unroll
        for (int ot = 0; ot < 4; ++ot)
#pragma unroll
            for (int r = 0; r < 4; ++r) Oa[ot][r] *= alpha[r];
        // P: C-layout -> A-layout via per-wave LDS buffer
#pragma unroll
        for (int nt = 0; nt < 6; ++nt)
#pragma unroll
            for (int r = 0; r < 4; ++r)
                Pl[wv][(fq * 4 + r) * PLS_ + nt * 16 + fr] = (__bf16)s[nt][r];
        __syncthreads();
        // O += P V   (B-fragment from swizzled Vt)
        bf16x8 ap[3];
#pragma unroll
        for (int kk = 0; kk < 3; ++kk)
            ap[kk] = *reinterpret_cast<const bf16x8*>(&Pl[wv][fr * PLS_ + kk * 32 + fq * 8]);
#pragma unroll
        for (int ot = 0; ot < 4; ++ot) {
            const int row = ot * 16 + fr;
#pragma unroll
            for (int kk = 0; kk < 3; ++kk) {
                bf16x8 bv = *reinterpret_cast<const bf16x8*>(&Vt[row * CK_ + vswz(kk * 4 + fq, row) * 8]);
                Oa[ot] = __builtin_amdgcn_mfma_f32_16x16x32_bf16(ap[kk], bv, Oa[ot], 0, 0, 0);
            }
        }
    }
    // epilogue: attn[b][n][h*64+hd] bf16
#pragma unroll
    for (int r = 0; r < 4; ++r) {
        const int n = q0 + wv * 16 + fq * 4 + r;
        if (n < 257) {
            const float inv = 1.0f / l_run[r];
#pragma unroll
            for (int ot = 0; ot < 4; ++ot)
                attn[((size_t)(bb * 257 + n)) * 1024 + hh * 64 + ot * 16 + fr] =
                    (__bf16)(Oa[ot][r] * inv);
        }
    }
}

// ---------------- output projection GEMM (bt) + bias -> f32 d_out ----------------
__global__ __launch_bounds__(256) void out_gemm(const __bf16* __restrict__ A,
                                                const __bf16* __restrict__ W,
                                                const float* __restrict__ bias,
                                                float* __restrict__ out) {
    __shared__ __align__(16) __bf16 As[128 * 32];
    __shared__ __align__(16) __bf16 Ws[128 * 32];
    const int tid  = threadIdx.x;
    const int row0 = blockIdx.x * 128, col0 = blockIdx.y * 128;
    const int lane = tid & 63, wv = tid >> 6;
    const int wm = (wv >> 1) * 64, wn = (wv & 1) * 64;
    const int fr = lane & 15, fq = lane >> 4;
    const int c1 = tid + 256;
    const size_t ga0 = (size_t)(row0 + (tid >> 2)) * 1024 + (tid & 3) * 8;
    const size_t ga1 = (size_t)(row0 + (c1 >> 2)) * 1024 + (c1 & 3) * 8;
    const size_t gw0 = (size_t)(col0 + (tid >> 2)) * 1024 + (tid & 3) * 8;
    const size_t gw1 = (size_t)(col0 + (c1 >> 2)) * 1024 + (c1 & 3) * 8;
    char* lbase0 = (char*)As + wv * 1024;
    char* lbase1 = (char*)As + wv * 1024 + 4096;
    char* lbw0 = (char*)Ws + wv * 1024;
    char* lbw1 = (char*)Ws + wv * 1024 + 4096;
    f32x4 acc[4][4] = {};
    for (int k0 = 0; k0 < 1024; k0 += 32) {
        gload_lds16(A + ga0 + k0, lbase0);
        gload_lds16(A + ga1 + k0, lbase1);
        gload_lds16(W + gw0 + k0, lbw0);
        gload_lds16(W + gw1 + k0, lbw1);
        __syncthreads();
        bf16x8 af[4], bfr[4];
#pragma unroll
        for (int i = 0; i < 4; ++i)
            af[i] = *reinterpret_cast<const bf16x8*>(&As[(wm + i * 16 + fr) * 32 + fq * 8]);
#pragma unroll
        for (int j = 0; j < 4; ++j)
            bfr[j] = *reinterpret_cast<const bf16x8*>(&Ws[(wn + j * 16 + fr) * 32 + fq * 8]);
#pragma unroll
        for (int i = 0; i < 4; ++i)
#pragma unroll
            for (int j = 0; j < 4; ++j)
                acc[i][j] = __builtin_amdgcn_mfma_f32_16x16x32_bf16(af[i], bfr[j], acc[i][j], 0, 0, 0);
        __syncthreads();
    }
    float bj[4];
#pragma unroll
    for (int j = 0; j < 4; ++j) bj[j] = bias[col0 + wn + j * 16 + fr];
#pragma unroll
    for (int i = 0; i < 4; ++i)
#pragma unroll
        for (int r = 0; r < 4; ++r) {
            const int m = row0 + wm + i * 16 + fq * 4 + r;
            if (m < M_) {
                float* p = out + (size_t)m * 1024 + col0 + wn + fr;
#pragma unroll
                for (int j = 0; j < 4; ++j) p[j * 16] = acc[i][j][r] + bj[j];
            }
        }
}

// ---------------- launch ----------------
// ws layout (bytes):
//   x_bf   @ 0          : MPAD*1024*2      = 33,816,576
//   w1_bf  @ 33816576   : 3072*1024*2      =  6,291,456
//   w2_bf  @ 40108032   : 1024*1024*2      =  2,097,152
//   q_ws   @ 42205184   : 64*16*257*64*2   = 33,685,504   [b][h][n][hd], pre-scaled 1/8
//   k_ws   @ 75890688   : 33,685,504                        [b][h][n][hd]
//   v_ws   @ 109576192  : 33,685,504                        [b][h][n][hd]
//   a_bf   @ 143261696  : MPAD*1024*2      = 33,816,576   attention output, bf16
extern "C" void kernel_launch(void* const* d_in, const int* in_sizes, int n_in,
                              void* d_out, int out_size, void* d_ws, size_t ws_size,
                              hipStream_t stream) {
    const float* x  = (const float*)d_in[0];
    const int* mask = (const int*)d_in[1];
    const float* w1 = (const float*)d_in[2];
    const float* b1 = (const float*)d_in[3];
    const float* w2 = (const float*)d_in[4];
    const float* b2 = (const float*)d_in[5];
    float* out = (float*)d_out;
    char* ws = (char*)d_ws;
    __bf16* x_bf  = (__bf16*)(ws);
    __bf16* w1_bf = (__bf16*)(ws + 33816576);
    __bf16* w2_bf = (__bf16*)(ws + 40108032);
    __bf16* q_ws  = (__bf16*)(ws + 42205184);
    __bf16* k_ws  = (__bf16*)(ws + 75890688);
    __bf16* v_ws  = (__bf16*)(ws + 109576192);
    __bf16* a_bf  = (__bf16*)(ws + 143261696);

    cvt_f32_bf16<<<16448, 256, 0, stream>>>(x, x_bf, 4210688);
    cvt_f32_bf16<<<3072, 256, 0, stream>>>(w1, w1_bf, 786432);
    cvt_f32_bf16<<<1024, 256, 0, stream>>>(w2, w2_bf, 262144);
    qkv_gemm<<<dim3(129, 24), 256, 0, stream>>>(x_bf, w1_bf, b1, q_ws, k_ws, v_ws);
    attn_kernel<<<dim3(1024, 5), 256, 0, stream>>>(q_ws, k_ws, v_ws, mask, a_bf);
    out_gemm<<<dim3(129, 8), 256, 0, stream>>>(a_bf, w2_bf, b2, out);
}

// Round 3
// 468.386 us; speedup vs baseline: 1.4501x; 1.0015x over previous
//
#include <hip/hip_runtime.h>

// Problem: B=64, N=257, D=1024, H=16, HD=64
#define B_   64
#define N_   257
#define D_   1024
#define H_   16
#define HD_  64
#define M_   (B_*N_)      // 16448 rows (b*257+n)
#define CK_  96           // attention key-chunk (3 chunks cover 288 >= 257)
#define VTS_ 128          // Vt row stride (16 groups of 8, swizzle domain)
#define PLS_ 104          // Pl row stride (8*odd -> spread banks)

typedef __bf16 bf16x8 __attribute__((ext_vector_type(8)));
typedef __bf16 bf16x4 __attribute__((ext_vector_type(4)));
typedef float  f32x4  __attribute__((ext_vector_type(4)));

// async global->LDS, 16B per lane; LDS dest = wave-uniform base + lane*16
__device__ __forceinline__ void gload_lds16(const void* g, void* l) {
    __builtin_amdgcn_global_load_lds(
        (const __attribute__((address_space(1))) void*)g,
        (__attribute__((address_space(3))) void*)l, 16, 0, 0);
}

// ---------------- f32 -> bf16 convert ----------------
__global__ __launch_bounds__(256) void cvt_f32_bf16(const float* __restrict__ src,
                                                    __bf16* __restrict__ dst, int n4) {
    int i = blockIdx.x * 256 + threadIdx.x;
    if (i >= n4) return;
    float4 v = reinterpret_cast<const float4*>(src)[i];
    bf16x4 o;
    o[0] = (__bf16)v.x; o[1] = (__bf16)v.y; o[2] = (__bf16)v.z; o[3] = (__bf16)v.w;
    *reinterpret_cast<bf16x4*>(dst + (size_t)i * 4) = o;
}

// ---------------- QKV projection GEMM (bt), BK=64, XOR-swizzled LDS ----------------
// LDS rows are 128B (8 groups of 16B); phys group = logical ^ (row&7), applied on the
// GLOBAL SOURCE side (global_load_lds dest is lane-pinned). Fragment reads land each
// 8-lane phase on 32 distinct banks -> conflict-free.
__global__ __launch_bounds__(256) void qkv_gemm(const __bf16* __restrict__ A,
                                                const __bf16* __restrict__ W,
                                                const float* __restrict__ bias,
                                                __bf16* __restrict__ qw,
                                                __bf16* __restrict__ kw,
                                                __bf16* __restrict__ vw) {
    __shared__ __align__(16) char smem[32768];
    __bf16* As = (__bf16*)smem;             // [128][64] swizzled
    __bf16* Ws = (__bf16*)(smem + 16384);   // [128][64] swizzled
    __bf16* Ct = (__bf16*)smem;             // [128][128] epilogue reuse
    const int tid  = threadIdx.x;
    const int row0 = blockIdx.x * 128, col0 = blockIdx.y * 128;
    const int lane = tid & 63, wv = tid >> 6;
    const int wm = (wv >> 1) * 64, wn = (wv & 1) * 64;
    const int fr = lane & 15, fq = lane >> 4;
    // staging source offsets (4 slots per matrix per thread), source-side swizzle
    size_t sA[4], sW[4];
#pragma unroll
    for (int i = 0; i < 4; ++i) {
        const int c = tid + i * 256;
        const int r = c >> 3, g = (c & 7) ^ (r & 7);
        sA[i] = (size_t)(row0 + r) * 1024 + g * 8;
        sW[i] = (size_t)(col0 + r) * 1024 + g * 8;
    }
    const int fsw = ((fr & 7)) * 8;  // fragment-read swizzle term (phys = (ks*4+fq)^ (fr&7))
    f32x4 acc[4][4] = {};
    for (int k0 = 0; k0 < 1024; k0 += 64) {
#pragma unroll
        for (int i = 0; i < 4; ++i) {
            gload_lds16(A + sA[i] + k0, (char*)As + i * 4096 + wv * 1024);
            gload_lds16(W + sW[i] + k0, (char*)Ws + i * 4096 + wv * 1024);
        }
        __syncthreads();
#pragma unroll
        for (int ks = 0; ks < 2; ++ks) {
            const int goff = (((ks * 4 + fq) ^ (fr & 7)) * 8);
            bf16x8 af[4], bw[4];
#pragma unroll
            for (int i = 0; i < 4; ++i)
                af[i] = *reinterpret_cast<const bf16x8*>(&As[(wm + i * 16 + fr) * 64 + goff]);
#pragma unroll
            for (int j = 0; j < 4; ++j)
                bw[j] = *reinterpret_cast<const bf16x8*>(&Ws[(wn + j * 16 + fr) * 64 + goff]);
#pragma unroll
            for (int i = 0; i < 4; ++i)
#pragma unroll
                for (int j = 0; j < 4; ++j)
                    acc[i][j] = __builtin_amdgcn_mfma_f32_16x16x32_bf16(af[i], bw[j], acc[i][j], 0, 0, 0);
        }
        __syncthreads();
    }
    // epilogue: C -> LDS (row-major 128x128) -> coalesced vectorized stores
    const int which = col0 >> 10;                 // block never straddles a 1024 boundary
    __bf16* dst = which == 0 ? qw : (which == 1 ? kw : vw);
    const float scale = which == 0 ? 0.125f : 1.0f;
    float bj[4];
#pragma unroll
    for (int j = 0; j < 4; ++j) bj[j] = bias[col0 + wn + j * 16 + fr];
#pragma unroll
    for (int i = 0; i < 4; ++i)
#pragma unroll
        for (int r = 0; r < 4; ++r) {
            const int row = wm + i * 16 + fq * 4 + r;
#pragma unroll
            for (int j = 0; j < 4; ++j)
                Ct[row * 128 + wn + j * 16 + fr] = (__bf16)((acc[i][j][r] + bj[j]) * scale);
        }
    __syncthreads();
    const int h0 = (col0 >> 6) & 15;
    const int col = (tid & 15) * 8;
    const int h = h0 + (col >> 6), hd = col & 63;
#pragma unroll
    for (int p = 0; p < 8; ++p) {
        const int row = p * 16 + (tid >> 4);
        const int m = row0 + row;
        if (m < M_) {
            bf16x8 v = *reinterpret_cast<const bf16x8*>(&Ct[row * 128 + col]);
            const int bb = m / 257, nn = m - bb * 257;
            *reinterpret_cast<bf16x8*>(dst + ((size_t)(bb * 16 + h) * 257 + nn) * 64 + hd) = v;
        }
    }
}

// ---------------- fused masked attention (flash-style, 3 key chunks of 96) ----------------
__global__ __launch_bounds__(256) void attn_kernel(const __bf16* __restrict__ qw,
                                                   const __bf16* __restrict__ kw,
                                                   const __bf16* __restrict__ vw,
                                                   const int* __restrict__ mask,
                                                   __bf16* __restrict__ attn) {
    const int bh = blockIdx.x;
    const int bb = bh >> 4, hh = bh & 15;
    const int q0 = blockIdx.y * 64;
    const int tid = threadIdx.x, lane = tid & 63, wv = tid >> 6;
    const int fr = lane & 15, fq = lane >> 4;
    const float NEG_INF = -__builtin_inff();

    __shared__ __align__(16) __bf16 Qs[64 * 64];        // [q][hd] swizzled (g ^= row&7)
    __shared__ __align__(16) __bf16 Ks[CK_ * 64];       // [key][hd] swizzled
    __shared__ __align__(16) __bf16 Vt[64 * VTS_];      // [hd][keygrp swizzled]
    __shared__ __align__(16) __bf16 Pl[4][16 * PLS_];   // per-wave P
    __shared__ float maskb[288];

    const __bf16* qg = qw + ((size_t)bh * 257 + q0) * 64;
    const __bf16* kg = kw + (size_t)bh * 257 * 64;
    const __bf16* vg = vw + (size_t)bh * 257 * 64;
    const int* mg = mask + bb * 257;

    // mask bias for all 288 key slots, once
    for (int idx = tid; idx < 288; idx += 256)
        maskb[idx] = (idx < 257 && mg[idx] == 0) ? 0.0f : NEG_INF;

    // stage Q tile [64][64] async, source-swizzled; rows past N keep stale LDS (never stored)
#pragma unroll
    for (int i = 0; i < 2; ++i) {
        const int c = tid + i * 256;
        const int r = c >> 3, g = (c & 7) ^ (r & 7);
        if (q0 + r < 257)
            gload_lds16(qg + (size_t)r * 64 + g * 8, (char*)Qs + i * 4096 + wv * 1024);
    }

    float m_run[4] = {NEG_INF, NEG_INF, NEG_INF, NEG_INF};
    float l_run[4] = {};
    f32x4 Oa[4] = {};

    for (int c3 = 0; c3 < 3; ++c3) {
        const int k0 = c3 * CK_;
        __syncthreads();  // prior-chunk readers done before restage (publishes maskb/Qs on c3==0)
        // stage K chunk [96][64] async, source-swizzled; stale rows masked to -inf (finite data)
#pragma unroll
        for (int i = 0; i < 3; ++i) {
            const int c = tid + i * 256;
            const int r = c >> 3, g = (c & 7) ^ (r & 7);
            if (k0 + r < 257)
                gload_lds16(kg + (size_t)(k0 + r) * 64 + g * 8, (char*)Ks + i * 4096 + wv * 1024);
        }
        // stage V^T: coalesced bf16x8 reads of V[key][hd], swizzled scalar LDS writes
#pragma unroll
        for (int it = 0; it < 3; ++it) {
            const int t = tid + it * 256;
            const int key = t >> 3, grp = t & 7;
            if (k0 + key < 257) {
                bf16x8 v8 = *reinterpret_cast<const bf16x8*>(vg + (size_t)(k0 + key) * 64 + grp * 8);
#pragma unroll
                for (int u = 0; u < 8; ++u) {
                    const int hd = grp * 8 + u;
                    Vt[hd * VTS_ + (((key >> 3) ^ (hd & 7)) * 8) + (key & 7)] = v8[u];
                }
            }
        }
        __syncthreads();

        // S = Q K^T (+ mask bias); q pre-scaled by 1/8
        f32x4 s[6];
        {
            bf16x8 aq[2];
#pragma unroll
            for (int ks = 0; ks < 2; ++ks)
                aq[ks] = *reinterpret_cast<const bf16x8*>(
                    &Qs[(wv * 16 + fr) * 64 + (((ks * 4 + fq) ^ (fr & 7)) * 8)]);
#pragma unroll
            for (int nt = 0; nt < 6; ++nt) {
                f32x4 sa = {};
#pragma unroll
                for (int ks = 0; ks < 2; ++ks) {
                    bf16x8 bk = *reinterpret_cast<const bf16x8*>(
                        &Ks[(nt * 16 + fr) * 64 + (((ks * 4 + fq) ^ (fr & 7)) * 8)]);
                    sa = __builtin_amdgcn_mfma_f32_16x16x32_bf16(aq[ks], bk, sa, 0, 0, 0);
                }
                const float mb = maskb[k0 + nt * 16 + fr];
#pragma unroll
                for (int r = 0; r < 4; ++r) sa[r] += mb;
                s[nt] = sa;
            }
        }
        // online softmax (row = fq*4+r, spread over 16 lanes)
        float alpha[4];
#pragma unroll
        for (int r = 0; r < 4; ++r) {
            float v = s[0][r];
#pragma unroll
            for (int nt = 1; nt < 6; ++nt) v = fmaxf(v, s[nt][r]);
            v = fmaxf(v, __shfl_xor(v, 1));
            v = fmaxf(v, __shfl_xor(v, 2));
            v = fmaxf(v, __shfl_xor(v, 4));
            v = fmaxf(v, __shfl_xor(v, 8));
            const float mnew = fmaxf(m_run[r], v);
            alpha[r] = __expf(m_run[r] - mnew);
            m_run[r] = mnew;
        }
        float sm[4] = {};
#pragma unroll
        for (int nt = 0; nt < 6; ++nt)
#pragma unroll
            for (int r = 0; r < 4; ++r) {
                const float p = __expf(s[nt][r] - m_run[r]);
                s[nt][r] = p;
                sm[r] += p;
            }
#pragma unroll
        for (int r = 0; r < 4; ++r) {
            float v = sm[r];
            v += __shfl_xor(v, 1);
            v += __shfl_xor(v, 2);
            v += __shfl_xor(v, 4);
            v += __shfl_xor(v, 8);
            l_run[r] = l_run[r] * alpha[r] + v;
        }
#pragma unroll
        for (int ot = 0; ot < 4; ++ot)
#pragma unroll
            for (int r = 0; r < 4; ++r) Oa[ot][r] *= alpha[r];
        // P: C-layout -> A-layout via per-wave LDS buffer
#pragma unroll
        for (int nt = 0; nt < 6; ++nt)
#pragma unroll
            for (int r = 0; r < 4; ++r)
                Pl[wv][(fq * 4 + r) * PLS_ + nt * 16 + fr] = (__bf16)s[nt][r];
        __syncthreads();
        // O += P V   (B-fragment from swizzled Vt)
        bf16x8 ap[3];
#pragma unroll
        for (int kk = 0; kk < 3; ++kk)
            ap[kk] = *reinterpret_cast<const bf16x8*>(&Pl[wv][fr * PLS_ + kk * 32 + fq * 8]);
#pragma unroll
        for (int ot = 0; ot < 4; ++ot) {
            const int row = ot * 16 + fr;
#pragma unroll
            for (int kk = 0; kk < 3; ++kk) {
                bf16x8 bv = *reinterpret_cast<const bf16x8*>(
                    &Vt[row * VTS_ + (((kk * 4 + fq) ^ (fr & 7)) * 8)]);
                Oa[ot] = __builtin_amdgcn_mfma_f32_16x16x32_bf16(ap[kk], bv, Oa[ot], 0, 0, 0);
            }
        }
    }
    // epilogue: attn[b][n][h*64+hd] bf16
#pragma unroll
    for (int r = 0; r < 4; ++r) {
        const int n = q0 + wv * 16 + fq * 4 + r;
        if (n < 257) {
            const float inv = 1.0f / l_run[r];
#pragma unroll
            for (int ot = 0; ot < 4; ++ot)
                attn[((size_t)(bb * 257 + n)) * 1024 + hh * 64 + ot * 16 + fr] =
                    (__bf16)(Oa[ot][r] * inv);
        }
    }
}

// ---------------- output projection GEMM (bt) + bias -> f32 d_out, BK=64 swizzled ----------------
__global__ __launch_bounds__(256) void out_gemm(const __bf16* __restrict__ A,
                                                const __bf16* __restrict__ W,
                                                const float* __restrict__ bias,
                                                float* __restrict__ out) {
    __shared__ __align__(16) char smem[32768];
    __bf16* As = (__bf16*)smem;
    __bf16* Ws = (__bf16*)(smem + 16384);
    const int tid  = threadIdx.x;
    const int row0 = blockIdx.x * 128, col0 = blockIdx.y * 128;
    const int lane = tid & 63, wv = tid >> 6;
    const int wm = (wv >> 1) * 64, wn = (wv & 1) * 64;
    const int fr = lane & 15, fq = lane >> 4;
    size_t sA[4], sW[4];
#pragma unroll
    for (int i = 0; i < 4; ++i) {
        const int c = tid + i * 256;
        const int r = c >> 3, g = (c & 7) ^ (r & 7);
        sA[i] = (size_t)(row0 + r) * 1024 + g * 8;
        sW[i] = (size_t)(col0 + r) * 1024 + g * 8;
    }
    f32x4 acc[4][4] = {};
    for (int k0 = 0; k0 < 1024; k0 += 64) {
#pragma unroll
        for (int i = 0; i < 4; ++i) {
            gload_lds16(A + sA[i] + k0, (char*)As + i * 4096 + wv * 1024);
            gload_lds16(W + sW[i] + k0, (char*)Ws + i * 4096 + wv * 1024);
        }
        __syncthreads();
#pragma unroll
        for (int ks = 0; ks < 2; ++ks) {
            const int goff = (((ks * 4 + fq) ^ (fr & 7)) * 8);
            bf16x8 af[4], bw[4];
#pragma unroll
            for (int i = 0; i < 4; ++i)
                af[i] = *reinterpret_cast<const bf16x8*>(&As[(wm + i * 16 + fr) * 64 + goff]);
#pragma unroll
            for (int j = 0; j < 4; ++j)
                bw[j] = *reinterpret_cast<const bf16x8*>(&Ws[(wn + j * 16 + fr) * 64 + goff]);
#pragma unroll
            for (int i = 0; i < 4; ++i)
#pragma unroll
                for (int j = 0; j < 4; ++j)
                    acc[i][j] = __builtin_amdgcn_mfma_f32_16x16x32_bf16(af[i], bw[j], acc[i][j], 0, 0, 0);
        }
        __syncthreads();
    }
    float bj[4];
#pragma unroll
    for (int j = 0; j < 4; ++j) bj[j] = bias[col0 + wn + j * 16 + fr];
#pragma unroll
    for (int i = 0; i < 4; ++i)
#pragma unroll
        for (int r = 0; r < 4; ++r) {
            const int m = row0 + wm + i * 16 + fq * 4 + r;
            if (m < M_) {
                float* p = out + (size_t)m * 1024 + col0 + wn + fr;
#pragma unroll
                for (int j = 0; j < 4; ++j) p[j * 16] = acc[i][j][r] + bj[j];
            }
        }
}

// ---------------- launch ----------------
// ws layout (bytes):
//   x_bf   @ 0          : 16512*1024*2    = 33,816,576
//   w1_bf  @ 33816576   : 3072*1024*2     =  6,291,456
//   w2_bf  @ 40108032   : 1024*1024*2     =  2,097,152
//   q_ws   @ 42205184   : 64*16*257*64*2  = 33,685,504   [b][h][n][hd], pre-scaled 1/8
//   k_ws   @ 75890688   : 33,685,504                      [b][h][n][hd]
//   v_ws   @ 109576192  : 33,685,504                      [b][h][n][hd]
//   a_bf   @ 143261696  : 33,816,576                      attention output, bf16
extern "C" void kernel_launch(void* const* d_in, const int* in_sizes, int n_in,
                              void* d_out, int out_size, void* d_ws, size_t ws_size,
                              hipStream_t stream) {
    const float* x  = (const float*)d_in[0];
    const int* mask = (const int*)d_in[1];
    const float* w1 = (const float*)d_in[2];
    const float* b1 = (const float*)d_in[3];
    const float* w2 = (const float*)d_in[4];
    const float* b2 = (const float*)d_in[5];
    float* out = (float*)d_out;
    char* ws = (char*)d_ws;
    __bf16* x_bf  = (__bf16*)(ws);
    __bf16* w1_bf = (__bf16*)(ws + 33816576);
    __bf16* w2_bf = (__bf16*)(ws + 40108032);
    __bf16* q_ws  = (__bf16*)(ws + 42205184);
    __bf16* k_ws  = (__bf16*)(ws + 75890688);
    __bf16* v_ws  = (__bf16*)(ws + 109576192);
    __bf16* a_bf  = (__bf16*)(ws + 143261696);

    cvt_f32_bf16<<<16448, 256, 0, stream>>>(x, x_bf, 4210688);
    cvt_f32_bf16<<<3072, 256, 0, stream>>>(w1, w1_bf, 786432);
    cvt_f32_bf16<<<1024, 256, 0, stream>>>(w2, w2_bf, 262144);
    qkv_gemm<<<dim3(129, 24), 256, 0, stream>>>(x_bf, w1_bf, b1, q_ws, k_ws, v_ws);
    attn_kernel<<<dim3(1024, 5), 256, 0, stream>>>(q_ws, k_ws, v_ws, mask, a_bf);
    out_gemm<<<dim3(129, 8), 256, 0, stream>>>(a_bf, w2_bf, b2, out);
}

// Round 4
// 452.744 us; speedup vs baseline: 1.5002x; 1.0346x over previous
//
#include <hip/hip_runtime.h>

// Problem: B=64, N=257, D=1024, H=16, HD=64
#define B_   64
#define N_   257
#define D_   1024
#define H_   16
#define HD_  64
#define M_   (B_*N_)      // 16448 rows (b*257+n)
#define CK_  96           // attention key-chunk (3 chunks cover 288 >= 257)
#define VTS_ 128          // Vt row stride
#define PLS_ 104          // Pl row stride (8*odd)

typedef __bf16 bf16x8 __attribute__((ext_vector_type(8)));
typedef __bf16 bf16x4 __attribute__((ext_vector_type(4)));
typedef float  f32x4  __attribute__((ext_vector_type(4)));

// async global->LDS, 16B per lane; LDS dest = wave-uniform base + lane*16
__device__ __forceinline__ void gload_lds16(const void* g, void* l) {
    __builtin_amdgcn_global_load_lds(
        (const __attribute__((address_space(1))) void*)g,
        (__attribute__((address_space(3))) void*)l, 16, 0, 0);
}

// ---------------- merged f32 -> bf16 convert (x, w1, w2 in one launch) ----------------
#define XQ_  4210688           // x quads
#define W1Q_ 786432            // w1 quads
#define W2Q_ 262144            // w2 quads
__global__ __launch_bounds__(256) void cvt_all(const float* __restrict__ x,
                                               const float* __restrict__ w1,
                                               const float* __restrict__ w2,
                                               __bf16* __restrict__ xb,
                                               __bf16* __restrict__ w1b,
                                               __bf16* __restrict__ w2b) {
    int i = blockIdx.x * 256 + threadIdx.x;
    const float* src; __bf16* dst; int j;
    if (i < XQ_) { src = x; dst = xb; j = i; }
    else if (i < XQ_ + W1Q_) { src = w1; dst = w1b; j = i - XQ_; }
    else if (i < XQ_ + W1Q_ + W2Q_) { src = w2; dst = w2b; j = i - XQ_ - W1Q_; }
    else return;
    float4 v = reinterpret_cast<const float4*>(src)[j];
    bf16x4 o;
    o[0] = (__bf16)v.x; o[1] = (__bf16)v.y; o[2] = (__bf16)v.z; o[3] = (__bf16)v.w;
    *reinterpret_cast<bf16x4*>(dst + (size_t)j * 4) = o;
}

// ---------------- QKV projection GEMM (bt), BK=64, swizzled LDS, XCD-partitioned grid ----
// 1D grid 3096. bid<3072: xcd=bid&7 owns rows xcd*16..+15 (A-slice = 4MB = one L2),
// sweeping cols (col = idx>>4). Tail 24 blocks: row 128, col 0..23.
__global__ __launch_bounds__(256) void qkv_gemm(const __bf16* __restrict__ A,
                                                const __bf16* __restrict__ W,
                                                const float* __restrict__ bias,
                                                __bf16* __restrict__ qw,
                                                __bf16* __restrict__ kw,
                                                __bf16* __restrict__ vw) {
    __shared__ __align__(16) char smem[32768];
    __bf16* As = (__bf16*)smem;             // [128][64] swizzled
    __bf16* Ws = (__bf16*)(smem + 16384);   // [128][64] swizzled
    __bf16* Ct = (__bf16*)smem;             // [128][128] epilogue reuse
    const int bid = blockIdx.x;
    int rowt, colt;
    if (bid < 3072) {
        const int xcd = bid & 7, idx = bid >> 3;
        colt = idx >> 4;                  // 0..23
        rowt = xcd * 16 + (idx & 15);     // 0..127
    } else {
        rowt = 128; colt = bid - 3072;    // 0..23
    }
    const int row0 = rowt * 128, col0 = colt * 128;
    const int tid  = threadIdx.x;
    const int lane = tid & 63, wv = tid >> 6;
    const int wm = (wv >> 1) * 64, wn = (wv & 1) * 64;
    const int fr = lane & 15, fq = lane >> 4;
    size_t sA[4], sW[4];
#pragma unroll
    for (int i = 0; i < 4; ++i) {
        const int c = tid + i * 256;
        const int r = c >> 3, g = (c & 7) ^ (r & 7);
        sA[i] = (size_t)(row0 + r) * 1024 + g * 8;
        sW[i] = (size_t)(col0 + r) * 1024 + g * 8;
    }
    f32x4 acc[4][4] = {};
    for (int k0 = 0; k0 < 1024; k0 += 64) {
#pragma unroll
        for (int i = 0; i < 4; ++i) {
            gload_lds16(A + sA[i] + k0, (char*)As + i * 4096 + wv * 1024);
            gload_lds16(W + sW[i] + k0, (char*)Ws + i * 4096 + wv * 1024);
        }
        __syncthreads();
#pragma unroll
        for (int ks = 0; ks < 2; ++ks) {
            const int goff = (((ks * 4 + fq) ^ (fr & 7)) * 8);
            bf16x8 af[4], bw[4];
#pragma unroll
            for (int i = 0; i < 4; ++i)
                af[i] = *reinterpret_cast<const bf16x8*>(&As[(wm + i * 16 + fr) * 64 + goff]);
#pragma unroll
            for (int j = 0; j < 4; ++j)
                bw[j] = *reinterpret_cast<const bf16x8*>(&Ws[(wn + j * 16 + fr) * 64 + goff]);
#pragma unroll
            for (int i = 0; i < 4; ++i)
#pragma unroll
                for (int j = 0; j < 4; ++j)
                    acc[i][j] = __builtin_amdgcn_mfma_f32_16x16x32_bf16(af[i], bw[j], acc[i][j], 0, 0, 0);
        }
        __syncthreads();
    }
    // epilogue: C -> LDS -> coalesced vectorized stores
    const int which = col0 >> 10;
    __bf16* dst = which == 0 ? qw : (which == 1 ? kw : vw);
    const float scale = which == 0 ? 0.125f : 1.0f;
    float bj[4];
#pragma unroll
    for (int j = 0; j < 4; ++j) bj[j] = bias[col0 + wn + j * 16 + fr];
#pragma unroll
    for (int i = 0; i < 4; ++i)
#pragma unroll
        for (int r = 0; r < 4; ++r) {
            const int row = wm + i * 16 + fq * 4 + r;
#pragma unroll
            for (int j = 0; j < 4; ++j)
                Ct[row * 128 + wn + j * 16 + fr] = (__bf16)((acc[i][j][r] + bj[j]) * scale);
        }
    __syncthreads();
    const int h0 = (col0 >> 6) & 15;
    const int col = (tid & 15) * 8;
    const int h = h0 + (col >> 6), hd = col & 63;
#pragma unroll
    for (int p = 0; p < 8; ++p) {
        const int row = p * 16 + (tid >> 4);
        const int m = row0 + row;
        if (m < M_) {
            bf16x8 v = *reinterpret_cast<const bf16x8*>(&Ct[row * 128 + col]);
            const int bb = m / 257, nn = m - bb * 257;
            *reinterpret_cast<bf16x8*>(dst + ((size_t)(bb * 16 + h) * 257 + nn) * 64 + hd) = v;
        }
    }
}

// ---------------- fused masked attention (rows 0..255; 3 key chunks of 96) ----------------
__global__ __launch_bounds__(256) void attn_kernel(const __bf16* __restrict__ qw,
                                                   const __bf16* __restrict__ kw,
                                                   const __bf16* __restrict__ vw,
                                                   const int* __restrict__ mask,
                                                   __bf16* __restrict__ attn) {
    const int bh = blockIdx.x;
    const int bb = bh >> 4, hh = bh & 15;
    const int q0 = blockIdx.y * 64;      // 0..192, all 64 rows valid
    const int tid = threadIdx.x, lane = tid & 63, wv = tid >> 6;
    const int fr = lane & 15, fq = lane >> 4;
    const float NEG_INF = -__builtin_inff();

    __shared__ __align__(16) __bf16 Qs[64 * 64];        // [q][hd] swizzled (g ^= row&7)
    __shared__ __align__(16) __bf16 Ks[CK_ * 64];       // [key][hd] swizzled
    __shared__ __align__(16) __bf16 Vt[64 * VTS_];      // [hd][keygrp swizzled]
    __shared__ __align__(16) __bf16 Pl[4][16 * PLS_];   // per-wave P
    __shared__ float maskb[288];

    const __bf16* qg = qw + ((size_t)bh * 257 + q0) * 64;
    const __bf16* kg = kw + (size_t)bh * 257 * 64;
    const __bf16* vg = vw + (size_t)bh * 257 * 64;
    const int* mg = mask + bb * 257;

    for (int idx = tid; idx < 288; idx += 256)
        maskb[idx] = (idx < 257 && mg[idx] == 0) ? 0.0f : NEG_INF;

    // stage Q tile [64][64] async, source-swizzled (all rows valid)
#pragma unroll
    for (int i = 0; i < 2; ++i) {
        const int c = tid + i * 256;
        const int r = c >> 3, g = (c & 7) ^ (r & 7);
        gload_lds16(qg + (size_t)r * 64 + g * 8, (char*)Qs + i * 4096 + wv * 1024);
    }

    float m_run[4] = {NEG_INF, NEG_INF, NEG_INF, NEG_INF};
    float l_run[4] = {};
    f32x4 Oa[4] = {};

    for (int c3 = 0; c3 < 3; ++c3) {
        const int k0 = c3 * CK_;
        __syncthreads();
#pragma unroll
        for (int i = 0; i < 3; ++i) {
            const int c = tid + i * 256;
            const int r = c >> 3, g = (c & 7) ^ (r & 7);
            if (k0 + r < 257)
                gload_lds16(kg + (size_t)(k0 + r) * 64 + g * 8, (char*)Ks + i * 4096 + wv * 1024);
        }
#pragma unroll
        for (int it = 0; it < 3; ++it) {
            const int t = tid + it * 256;
            const int key = t >> 3, grp = t & 7;
            if (k0 + key < 257) {
                bf16x8 v8 = *reinterpret_cast<const bf16x8*>(vg + (size_t)(k0 + key) * 64 + grp * 8);
#pragma unroll
                for (int u = 0; u < 8; ++u) {
                    const int hd = grp * 8 + u;
                    Vt[hd * VTS_ + (((key >> 3) ^ (hd & 7)) * 8) + (key & 7)] = v8[u];
                }
            }
        }
        __syncthreads();

        // S = Q K^T (+ mask bias); q pre-scaled by 1/8
        f32x4 s[6];
        {
            bf16x8 aq[2];
#pragma unroll
            for (int ks = 0; ks < 2; ++ks)
                aq[ks] = *reinterpret_cast<const bf16x8*>(
                    &Qs[(wv * 16 + fr) * 64 + (((ks * 4 + fq) ^ (fr & 7)) * 8)]);
#pragma unroll
            for (int nt = 0; nt < 6; ++nt) {
                f32x4 sa = {};
#pragma unroll
                for (int ks = 0; ks < 2; ++ks) {
                    bf16x8 bk = *reinterpret_cast<const bf16x8*>(
                        &Ks[(nt * 16 + fr) * 64 + (((ks * 4 + fq) ^ (fr & 7)) * 8)]);
                    sa = __builtin_amdgcn_mfma_f32_16x16x32_bf16(aq[ks], bk, sa, 0, 0, 0);
                }
                const float mb = maskb[k0 + nt * 16 + fr];
#pragma unroll
                for (int r = 0; r < 4; ++r) sa[r] += mb;
                s[nt] = sa;
            }
        }
        float alpha[4];
#pragma unroll
        for (int r = 0; r < 4; ++r) {
            float v = s[0][r];
#pragma unroll
            for (int nt = 1; nt < 6; ++nt) v = fmaxf(v, s[nt][r]);
            v = fmaxf(v, __shfl_xor(v, 1));
            v = fmaxf(v, __shfl_xor(v, 2));
            v = fmaxf(v, __shfl_xor(v, 4));
            v = fmaxf(v, __shfl_xor(v, 8));
            const float mnew = fmaxf(m_run[r], v);
            alpha[r] = __expf(m_run[r] - mnew);
            m_run[r] = mnew;
        }
        float sm[4] = {};
#pragma unroll
        for (int nt = 0; nt < 6; ++nt)
#pragma unroll
            for (int r = 0; r < 4; ++r) {
                const float p = __expf(s[nt][r] - m_run[r]);
                s[nt][r] = p;
                sm[r] += p;
            }
#pragma unroll
        for (int r = 0; r < 4; ++r) {
            float v = sm[r];
            v += __shfl_xor(v, 1);
            v += __shfl_xor(v, 2);
            v += __shfl_xor(v, 4);
            v += __shfl_xor(v, 8);
            l_run[r] = l_run[r] * alpha[r] + v;
        }
#pragma unroll
        for (int ot = 0; ot < 4; ++ot)
#pragma unroll
            for (int r = 0; r < 4; ++r) Oa[ot][r] *= alpha[r];
#pragma unroll
        for (int nt = 0; nt < 6; ++nt)
#pragma unroll
            for (int r = 0; r < 4; ++r)
                Pl[wv][(fq * 4 + r) * PLS_ + nt * 16 + fr] = (__bf16)s[nt][r];
        __syncthreads();
        bf16x8 ap[3];
#pragma unroll
        for (int kk = 0; kk < 3; ++kk)
            ap[kk] = *reinterpret_cast<const bf16x8*>(&Pl[wv][fr * PLS_ + kk * 32 + fq * 8]);
#pragma unroll
        for (int ot = 0; ot < 4; ++ot) {
            const int row = ot * 16 + fr;
#pragma unroll
            for (int kk = 0; kk < 3; ++kk) {
                bf16x8 bv = *reinterpret_cast<const bf16x8*>(
                    &Vt[row * VTS_ + (((kk * 4 + fq) ^ (fr & 7)) * 8)]);
                Oa[ot] = __builtin_amdgcn_mfma_f32_16x16x32_bf16(ap[kk], bv, Oa[ot], 0, 0, 0);
            }
        }
    }
    // epilogue (all rows valid)
#pragma unroll
    for (int r = 0; r < 4; ++r) {
        const int n = q0 + wv * 16 + fq * 4 + r;
        const float inv = 1.0f / l_run[r];
#pragma unroll
        for (int ot = 0; ot < 4; ++ot)
            attn[((size_t)(bb * 257 + n)) * 1024 + hh * 64 + ot * 16 + fr] =
                (__bf16)(Oa[ot][r] * inv);
    }
}

// ---------------- attention tail: query row 256, one block per (b,h) ----------------
__global__ __launch_bounds__(320) void attn_tail(const __bf16* __restrict__ qw,
                                                 const __bf16* __restrict__ kw,
                                                 const __bf16* __restrict__ vw,
                                                 const int* __restrict__ mask,
                                                 __bf16* __restrict__ attn) {
    const int bh = blockIdx.x;
    const int bb = bh >> 4, hh = bh & 15;
    const int tid = threadIdx.x, wv = tid >> 6;
    const float NEG_INF = -__builtin_inff();
    __shared__ float pbuf[257];
    __shared__ float red[5];
    __shared__ float gstat[2];   // [0]=max, [1]=sum

    const __bf16* qg = qw + ((size_t)bh * 257 + 256) * 64;
    const __bf16* kg = kw + (size_t)bh * 257 * 64;
    const __bf16* vg = vw + (size_t)bh * 257 * 64;

    float s = NEG_INF;
    if (tid < 257) {
        const __bf16* kr = kg + (size_t)tid * 64;
        float acc = 0.0f;
#pragma unroll
        for (int g = 0; g < 8; ++g) {
            bf16x8 qv = *reinterpret_cast<const bf16x8*>(qg + g * 8);
            bf16x8 kv = *reinterpret_cast<const bf16x8*>(kr + g * 8);
#pragma unroll
            for (int u = 0; u < 8; ++u) acc += (float)qv[u] * (float)kv[u];
        }
        s = (mask[bb * 257 + tid] == 0) ? acc : NEG_INF;   // q pre-scaled by 1/8
    }
    // block max
    float v = s;
#pragma unroll
    for (int d = 1; d < 64; d <<= 1) v = fmaxf(v, __shfl_xor(v, d));
    if ((tid & 63) == 0) red[wv] = v;
    __syncthreads();
    if (tid == 0) {
        float m = red[0];
#pragma unroll
        for (int w = 1; w < 5; ++w) m = fmaxf(m, red[w]);
        gstat[0] = m;
    }
    __syncthreads();
    const float gmax = gstat[0];
    float p = (tid < 257) ? __expf(s - gmax) : 0.0f;
    if (tid < 257) pbuf[tid] = p;
    float sv = p;
#pragma unroll
    for (int d = 1; d < 64; d <<= 1) sv += __shfl_xor(sv, d);
    if ((tid & 63) == 0) red[wv] = sv;
    __syncthreads();
    if (tid == 0) gstat[1] = red[0] + red[1] + red[2] + red[3] + red[4];
    __syncthreads();
    if (tid < 64) {
        const float inv = 1.0f / gstat[1];
        float o = 0.0f;
        for (int j = 0; j < 257; ++j)
            o += pbuf[j] * (float)vg[(size_t)j * 64 + tid];
        attn[((size_t)(bb * 257 + 256)) * 1024 + hh * 64 + tid] = (__bf16)(o * inv);
    }
}

// ---------------- output projection GEMM (bt) + bias -> f32, XCD-partitioned ----------------
__global__ __launch_bounds__(256) void out_gemm(const __bf16* __restrict__ A,
                                                const __bf16* __restrict__ W,
                                                const float* __restrict__ bias,
                                                float* __restrict__ out) {
    __shared__ __align__(16) char smem[32768];
    __bf16* As = (__bf16*)smem;
    __bf16* Ws = (__bf16*)(smem + 16384);
    const int bid = blockIdx.x;
    int rowt, colt;
    if (bid < 1024) {
        const int xcd = bid & 7, idx = bid >> 3;
        colt = idx >> 4;                  // 0..7
        rowt = xcd * 16 + (idx & 15);     // 0..127
    } else {
        rowt = 128; colt = bid - 1024;    // 0..7
    }
    const int row0 = rowt * 128, col0 = colt * 128;
    const int tid  = threadIdx.x;
    const int lane = tid & 63, wv = tid >> 6;
    const int wm = (wv >> 1) * 64, wn = (wv & 1) * 64;
    const int fr = lane & 15, fq = lane >> 4;
    size_t sA[4], sW[4];
#pragma unroll
    for (int i = 0; i < 4; ++i) {
        const int c = tid + i * 256;
        const int r = c >> 3, g = (c & 7) ^ (r & 7);
        sA[i] = (size_t)(row0 + r) * 1024 + g * 8;
        sW[i] = (size_t)(col0 + r) * 1024 + g * 8;
    }
    f32x4 acc[4][4] = {};
    for (int k0 = 0; k0 < 1024; k0 += 64) {
#pragma unroll
        for (int i = 0; i < 4; ++i) {
            gload_lds16(A + sA[i] + k0, (char*)As + i * 4096 + wv * 1024);
            gload_lds16(W + sW[i] + k0, (char*)Ws + i * 4096 + wv * 1024);
        }
        __syncthreads();
#pragma unroll
        for (int ks = 0; ks < 2; ++ks) {
            const int goff = (((ks * 4 + fq) ^ (fr & 7)) * 8);
            bf16x8 af[4], bw[4];
#pragma unroll
            for (int i = 0; i < 4; ++i)
                af[i] = *reinterpret_cast<const bf16x8*>(&As[(wm + i * 16 + fr) * 64 + goff]);
#pragma unroll
            for (int j = 0; j < 4; ++j)
                bw[j] = *reinterpret_cast<const bf16x8*>(&Ws[(wn + j * 16 + fr) * 64 + goff]);
#pragma unroll
            for (int i = 0; i < 4; ++i)
#pragma unroll
                for (int j = 0; j < 4; ++j)
                    acc[i][j] = __builtin_amdgcn_mfma_f32_16x16x32_bf16(af[i], bw[j], acc[i][j], 0, 0, 0);
        }
        __syncthreads();
    }
    float bj[4];
#pragma unroll
    for (int j = 0; j < 4; ++j) bj[j] = bias[col0 + wn + j * 16 + fr];
#pragma unroll
    for (int i = 0; i < 4; ++i)
#pragma unroll
        for (int r = 0; r < 4; ++r) {
            const int m = row0 + wm + i * 16 + fq * 4 + r;
            if (m < M_) {
                float* p = out + (size_t)m * 1024 + col0 + wn + fr;
#pragma unroll
                for (int j = 0; j < 4; ++j) p[j * 16] = acc[i][j][r] + bj[j];
            }
        }
}

// ---------------- launch ----------------
// ws layout (bytes):
//   x_bf   @ 0          : 16512*1024*2    = 33,816,576
//   w1_bf  @ 33816576   : 3072*1024*2     =  6,291,456
//   w2_bf  @ 40108032   : 1024*1024*2     =  2,097,152
//   q_ws   @ 42205184   : 64*16*257*64*2  = 33,685,504   [b][h][n][hd], pre-scaled 1/8
//   k_ws   @ 75890688   : 33,685,504                      [b][h][n][hd]
//   v_ws   @ 109576192  : 33,685,504                      [b][h][n][hd]
//   a_bf   @ 143261696  : 33,816,576                      attention output, bf16
extern "C" void kernel_launch(void* const* d_in, const int* in_sizes, int n_in,
                              void* d_out, int out_size, void* d_ws, size_t ws_size,
                              hipStream_t stream) {
    const float* x  = (const float*)d_in[0];
    const int* mask = (const int*)d_in[1];
    const float* w1 = (const float*)d_in[2];
    const float* b1 = (const float*)d_in[3];
    const float* w2 = (const float*)d_in[4];
    const float* b2 = (const float*)d_in[5];
    float* out = (float*)d_out;
    char* ws = (char*)d_ws;
    __bf16* x_bf  = (__bf16*)(ws);
    __bf16* w1_bf = (__bf16*)(ws + 33816576);
    __bf16* w2_bf = (__bf16*)(ws + 40108032);
    __bf16* q_ws  = (__bf16*)(ws + 42205184);
    __bf16* k_ws  = (__bf16*)(ws + 75890688);
    __bf16* v_ws  = (__bf16*)(ws + 109576192);
    __bf16* a_bf  = (__bf16*)(ws + 143261696);

    cvt_all<<<20544, 256, 0, stream>>>(x, w1, w2, x_bf, w1_bf, w2_bf);
    qkv_gemm<<<3096, 256, 0, stream>>>(x_bf, w1_bf, b1, q_ws, k_ws, v_ws);
    attn_kernel<<<dim3(1024, 4), 256, 0, stream>>>(q_ws, k_ws, v_ws, mask, a_bf);
    attn_tail<<<1024, 320, 0, stream>>>(q_ws, k_ws, v_ws, mask, a_bf);
    out_gemm<<<1032, 256, 0, stream>>>(a_bf, w2_bf, b2, out);
}